// Round 10
// baseline (311.467 us; speedup 1.0000x reference)
//
#include <hip/hip_runtime.h>
#include <hip/hip_fp16.h>

// Qwen3 attention block: B=2 S=2048 HID=1024 NH=16 NKV=8 HD=128, causal.
// R10: R9 with the epilogue addressing bug fixed: Q/K phase-2 store was
//      missing the s0 tile offset (wrote all tiles into s in [0,128)).
//      Fused QKV GEMM + RMSNorm + RoPE + transpose; attn = R8 (86 us).

typedef _Float16 f16;
typedef __attribute__((ext_vector_type(8))) _Float16 f16x8;
typedef __attribute__((ext_vector_type(4))) _Float16 f16x4;
typedef __attribute__((ext_vector_type(4))) float f32x4;

__constant__ const float kEps = 1e-6f;
// 1/sqrt(128) * log2(e): Q pre-scaled so attn softmax runs in exp2 domain
__constant__ const float kScaleL2 = 0.1275179120685481f;

// async global->LDS, 16B/lane; lds ptr must be wave-uniform (HW adds lane*16)
#define ASYNC_LD16(gp, lp)                                              \
  __builtin_amdgcn_global_load_lds(                                     \
      (const __attribute__((address_space(1))) void*)(gp),              \
      (__attribute__((address_space(3))) void*)(uint32_t)(uintptr_t)(lp), 16, 0, 0)

__device__ __forceinline__ float dpp_sum16(float v) {
  int x;
  x = __builtin_amdgcn_update_dpp(0, __builtin_bit_cast(int, v), 0xB1, 0xF, 0xF, true);
  v += __builtin_bit_cast(float, x);
  x = __builtin_amdgcn_update_dpp(0, __builtin_bit_cast(int, v), 0x4E, 0xF, 0xF, true);
  v += __builtin_bit_cast(float, x);
  x = __builtin_amdgcn_update_dpp(0, __builtin_bit_cast(int, v), 0x141, 0xF, 0xF, true);
  v += __builtin_bit_cast(float, x);
  x = __builtin_amdgcn_update_dpp(0, __builtin_bit_cast(int, v), 0x140, 0xF, 0xF, true);
  v += __builtin_bit_cast(float, x);
  return v;
}

// ------------------------------------------------ fused cast f32->f16 (all 5)
__global__ __launch_bounds__(256) void cast_all(
    const float* __restrict__ h, const float* __restrict__ wq,
    const float* __restrict__ wk, const float* __restrict__ wv,
    const float* __restrict__ wo, f16* __restrict__ hb,
    f16* __restrict__ wqkv, f16* __restrict__ wob) {
  const int idx = blockIdx.x * 256 + threadIdx.x;
  const float* src;
  f16* dst;
  int base;
  if (idx < 1048576) { src = h;  dst = hb;                  base = 0; }
  else if (idx < 1572864) { src = wq; dst = wqkv;               base = 1048576; }
  else if (idx < 1835008) { src = wk; dst = wqkv + 2048 * 1024; base = 1572864; }
  else if (idx < 2097152) { src = wv; dst = wqkv + 3072 * 1024; base = 1835008; }
  else { src = wo; dst = wob; base = 2097152; }
  const int i = (idx - base) * 4;
  f32x4 v = *reinterpret_cast<const f32x4*>(src + i);
  f16x4 o;
  o.x = (f16)v.x; o.y = (f16)v.y; o.z = (f16)v.z; o.w = (f16)v.w;
  *reinterpret_cast<f16x4*>(dst + i) = o;
}

// ------------------- fused QKV projection + RMSNorm + RoPE + transpose
// A: hb (4096 x 1024), Bm: wqkv rows [Wq;Wk;Wv] (4096 x 1024).
// tn<16: Q head tn -> qt[(b*16+h)*2048 + s][d] (scaled by kScaleL2)
// tn in [16,24): K head tn-16 -> kt[(b*8+h)*2048 + s][d]
// tn >= 24: V head tn-24 -> vt[(b*8+h)*128 + d][s]  (direct from regs)
__global__ __launch_bounds__(256) void gemm_qkv(
    const f16* __restrict__ A, const f16* __restrict__ Bm,
    const float* __restrict__ qnw, const float* __restrict__ knw,
    const float* __restrict__ cosT, const float* __restrict__ sinT,
    f16* __restrict__ qt, f16* __restrict__ kt, f16* __restrict__ vt) {
  // LDS: mainloop uses [0,32K) as As/Bs; epilogue reuses [0,34.8K) as the
  // 128x136 f16 tile (safe: last mainloop barrier precedes tile writes).
  __shared__ __align__(16) char smem[35840];
  f16 (*As)[64] = reinterpret_cast<f16(*)[64]>(smem);
  f16 (*Bs)[64] = reinterpret_cast<f16(*)[64]>(smem + 16384);
  f16 (*Ct)[136] = reinterpret_cast<f16(*)[136]>(smem);
  float* rsq = reinterpret_cast<float*>(smem + 34816);  // [2][128]

  const int K = 1024, tn = blockIdx.x, tm = blockIdx.y;
  const int tid = threadIdx.x;
  const int lane = tid & 63;
  const int wave = tid >> 6;
  const int cl = lane & 15;
  const int quad = lane >> 4;
  const int wm = (wave >> 1) * 64;
  const int wn = (wave & 1) * 64;
  const int r0 = tid >> 3;
  const int csw = ((tid & 7) ^ (r0 & 7)) * 8;

  const f16* Ab = A + (size_t)(tm * 128 + r0) * K + csw;
  const f16* Bb = Bm + (size_t)(tn * 128 + r0) * K + csw;
  char* Al = smem + wave * 1024;
  char* Bl = smem + 16384 + wave * 1024;

  f32x4 acc[4][4] = {};

  for (int k0 = 0; k0 < K; k0 += 64) {
#pragma unroll
    for (int c = 0; c < 4; ++c) {
      ASYNC_LD16(Ab + (size_t)(c * 32) * K + k0, Al + c * 4096);
      ASYNC_LD16(Bb + (size_t)(c * 32) * K + k0, Bl + c * 4096);
    }
    __syncthreads();
#pragma unroll
    for (int kk = 0; kk < 2; ++kk) {
      f16x8 af[4], bf[4];
#pragma unroll
      for (int mi = 0; mi < 4; ++mi)
        af[mi] = *reinterpret_cast<const f16x8*>(
            &As[wm + mi * 16 + cl][((kk * 4 + quad) ^ (cl & 7)) * 8]);
#pragma unroll
      for (int ni = 0; ni < 4; ++ni)
        bf[ni] = *reinterpret_cast<const f16x8*>(
            &Bs[wn + ni * 16 + cl][((kk * 4 + quad) ^ (cl & 7)) * 8]);
#pragma unroll
      for (int mi = 0; mi < 4; ++mi)
#pragma unroll
        for (int ni = 0; ni < 4; ++ni)
          acc[mi][ni] =
              __builtin_amdgcn_mfma_f32_16x16x32_f16(af[mi], bf[ni], acc[mi][ni], 0, 0, 0);
    }
    __syncthreads();
  }

  const int b = tm >> 4;            // M row = b*2048 + s; s0 = (tm&15)*128
  const int s0 = (tm & 15) * 128;

  // ---------------- V blocks: direct transposed stores from registers
  if (tn >= 24) {
    const int h = tn - 24;
    f16* vbase = vt + (size_t)(b * 8 + h) * 128 * 2048;
#pragma unroll
    for (int mi = 0; mi < 4; ++mi) {
      const int sg = s0 + wm + mi * 16 + quad * 4;
#pragma unroll
      for (int ni = 0; ni < 4; ++ni) {
        const int d = wn + ni * 16 + cl;
        f16x4 o;
#pragma unroll
        for (int r = 0; r < 4; ++r) o[r] = (f16)acc[mi][ni][r];
        *reinterpret_cast<f16x4*>(vbase + (size_t)d * 2048 + sg) = o;
      }
    }
    return;
  }

  // ---------------- Q/K blocks: RMSNorm + RoPE + (s,d) store
  // phase 1: row sum-of-squares (f32 accs) + raw tile to LDS (f16)
  float s2[4][4];
#pragma unroll
  for (int mi = 0; mi < 4; ++mi)
#pragma unroll
    for (int r = 0; r < 4; ++r) {
      float v = 0.f;
#pragma unroll
      for (int ni = 0; ni < 4; ++ni) v += acc[mi][ni][r] * acc[mi][ni][r];
      s2[mi][r] = dpp_sum16(v);   // sum over this wave's 64 cols
    }
#pragma unroll
  for (int mi = 0; mi < 4; ++mi) {
    const int srow = wm + mi * 16 + quad * 4;
    if (cl == 0) {
#pragma unroll
      for (int r = 0; r < 4; ++r)
        rsq[(wave & 1) * 128 + srow + r] = s2[mi][r];
    }
#pragma unroll
    for (int ni = 0; ni < 4; ++ni) {
      const int d = wn + ni * 16 + cl;
#pragma unroll
      for (int r = 0; r < 4; ++r) Ct[srow + r][d] = (f16)acc[mi][ni][r];
    }
  }
  __syncthreads();

  // phase 2: 128 rows x 16 chunks of 8 d; coalesced b128 stores
  const bool isq = tn < 16;
  const int h = isq ? tn : tn - 16;
  const float* wv_ = isq ? qnw : knw;
  const float osc = isq ? kScaleL2 : 1.0f;
  f16* obase = isq ? qt + (size_t)(b * 16 + h) * 2048 * 128
                   : kt + (size_t)(b * 8 + h) * 2048 * 128;
#pragma unroll
  for (int i = 0; i < 8; ++i) {
    const int idx = tid + i * 256;
    const int srow = idx >> 4;
    const int d0 = (idx & 15) * 8;
    const int dp = d0 ^ 64;                    // rotate-half partner
    const float sgn = (d0 < 64) ? -1.f : 1.f;
    const float rq = rsq[srow] + rsq[128 + srow];
    const float rms = rsqrtf(rq * (1.0f / 128.0f) + kEps);
    const int grow = tm * 128 + srow;          // = b*2048 + s0 + srow
    const float* cb = cosT + (size_t)grow * 128;
    const float* sb = sinT + (size_t)grow * 128;
    f16x8 x = *reinterpret_cast<const f16x8*>(&Ct[srow][d0]);
    f16x8 xp = *reinterpret_cast<const f16x8*>(&Ct[srow][dp]);
    f16x8 o;
#pragma unroll
    for (int j = 0; j < 8; ++j) {
      const float n = (float)x[j] * rms * wv_[d0 + j];
      const float np = (float)xp[j] * rms * wv_[dp + j];
      o[j] = (f16)((n * cb[d0 + j] + sgn * np * sb[d0 + j]) * osc);
    }
    // FIX (R9 bug): include the s0 tile offset in the output row.
    *reinterpret_cast<f16x8*>(obase + (size_t)(s0 + srow) * 128 + d0) = o;
  }
}

// --------------------------- C[M,N] = A[M,K]*B[N,K]^T, f32 out (out proj)
__global__ __launch_bounds__(256) void gemm_bt64(const f16* __restrict__ A,
                                                 const f16* __restrict__ Bm,
                                                 float* __restrict__ C,
                                                 int M, int N, int K) {
  __shared__ __align__(16) f16 As[64][64];
  __shared__ __align__(16) f16 Bs[128][64];
  const int tid = threadIdx.x;
  const int lane = tid & 63;
  const int wave = tid >> 6;
  const int cl = lane & 15;
  const int quad = lane >> 4;
  const int wm = (wave >> 1) * 32;
  const int wn = (wave & 1) * 64;
  const int tm = blockIdx.y * 64;
  const int tn = blockIdx.x * 128;
  const int r0 = tid >> 3;
  const int csw = ((tid & 7) ^ (r0 & 7)) * 8;

  const f16* Ab = A + (size_t)(tm + r0) * K + csw;
  const f16* Bb = Bm + (size_t)(tn + r0) * K + csw;
  char* Al = (char*)As + wave * 1024;
  char* Bl = (char*)Bs + wave * 1024;

  f32x4 acc[2][4] = {};

  for (int k0 = 0; k0 < K; k0 += 64) {
#pragma unroll
    for (int c = 0; c < 2; ++c)
      ASYNC_LD16(Ab + (size_t)(c * 32) * K + k0, Al + c * 4096);
#pragma unroll
    for (int c = 0; c < 4; ++c)
      ASYNC_LD16(Bb + (size_t)(c * 32) * K + k0, Bl + c * 4096);
    __syncthreads();
#pragma unroll
    for (int kk = 0; kk < 2; ++kk) {
      f16x8 af[2], bf[4];
#pragma unroll
      for (int mi = 0; mi < 2; ++mi)
        af[mi] = *reinterpret_cast<const f16x8*>(
            &As[wm + mi * 16 + cl][((kk * 4 + quad) ^ (cl & 7)) * 8]);
#pragma unroll
      for (int ni = 0; ni < 4; ++ni)
        bf[ni] = *reinterpret_cast<const f16x8*>(
            &Bs[wn + ni * 16 + cl][((kk * 4 + quad) ^ (cl & 7)) * 8]);
#pragma unroll
      for (int mi = 0; mi < 2; ++mi)
#pragma unroll
        for (int ni = 0; ni < 4; ++ni)
          acc[mi][ni] =
              __builtin_amdgcn_mfma_f32_16x16x32_f16(af[mi], bf[ni], acc[mi][ni], 0, 0, 0);
    }
    __syncthreads();
  }
#pragma unroll
  for (int mi = 0; mi < 2; ++mi)
#pragma unroll
    for (int ni = 0; ni < 4; ++ni)
#pragma unroll
      for (int r = 0; r < 4; ++r)
        C[(size_t)(tm + wm + mi * 16 + quad * 4 + r) * N + tn + wn + ni * 16 + cl] =
            acc[mi][ni][r];
}

// ------------------------------------------------------- flash attention (causal)
// (identical to R8's measured-good version: 1024 blocks x 128 thr, S^T=K*Q^T,
//  per-lane softmax, b64 Ps, PV transposed on 16x16x32, async XOR staging)
__global__ __launch_bounds__(128) void attn(const f16* __restrict__ Qt,
                                            const f16* __restrict__ Kt,
                                            const f16* __restrict__ Vt,
                                            f16* __restrict__ Ot) {
  __shared__ __align__(16) f16 Ks[64 * 128];   // 16 KB swizzled (s,d)
  __shared__ __align__(16) f16 Vs[128 * 64];   // 16 KB swizzled (d,s)
  __shared__ __align__(16) f16 Ps[2][32][72];  // 9 KB  [wave][q][s]

  const int bid = blockIdx.x;
  const int bh = bid & 31;
  const int t = 31 - (bid >> 5);   // longest tiles first
  const int q0 = t * 64;
  const int b = bh >> 4, h = bh & 15;
  const int kv = h >> 1;

  const int tid = threadIdx.x;
  const int lane = tid & 63, wv = tid >> 6;
  const int cl = lane & 15, quad = lane >> 4;
  const int qw0 = q0 + wv * 32;               // wave's first q-row

  const f16* qbase = Qt + ((size_t)(b * 16 + h) * 2048 + qw0 + cl) * 128;
  f16x8 aq[2][4];
#pragma unroll
  for (int mi = 0; mi < 2; ++mi)
#pragma unroll
    for (int kk = 0; kk < 4; ++kk)
      aq[mi][kk] =
          *reinterpret_cast<const f16x8*>(qbase + mi * 16 * 128 + kk * 32 + quad * 8);

  const f16* kbase = Kt + (size_t)(b * 8 + kv) * 2048 * 128;
  const f16* vbase = Vt + (size_t)(b * 8 + kv) * 128 * 2048;

  float m_[2] = {-1e30f, -1e30f}, l_[2] = {0.f, 0.f};  // per-lane q state
  f32x4 oacc[2][8] = {};                                // D[m=d][n=q=cl]

  for (int kt0 = 0; kt0 <= q0; kt0 += 64) {
#pragma unroll
    for (int i = 0; i < 8; ++i) {
      const int c = (wv * 8 + i) * 64 + lane;
      const int kr = c >> 4, kg = c & 15;
      const int kgs = (kg & 8) | ((kg & 7) ^ (kr & 7));
      ASYNC_LD16(kbase + (size_t)(kt0 + kr) * 128 + kgs * 8,
                 (char*)Ks + (wv * 8 + i) * 1024);
      const int vr = c >> 3, vg = c & 7;
      const int vgs = vg ^ (vr & 7);
      ASYNC_LD16(vbase + (size_t)vr * 2048 + kt0 + vgs * 8,
                 (char*)Vs + (wv * 8 + i) * 1024);
    }
    __syncthreads();
    f32x4 sacc[2][4] = {};
#pragma unroll
    for (int kk = 0; kk < 4; ++kk)
#pragma unroll
      for (int ni = 0; ni < 4; ++ni) {
        const int gk = kk * 4 + quad;
        const int gks = (gk & 8) | ((gk & 7) ^ (cl & 7));
        f16x8 ak =
            *reinterpret_cast<const f16x8*>(Ks + (ni * 16 + cl) * 128 + gks * 8);
#pragma unroll
        for (int mi = 0; mi < 2; ++mi)
          sacc[mi][ni] =
              __builtin_amdgcn_mfma_f32_16x16x32_f16(ak, aq[mi][kk], sacc[mi][ni], 0, 0, 0);
      }
    if (kt0 == q0) {
#pragma unroll
      for (int mi = 0; mi < 2; ++mi) {
        const int qg = qw0 + mi * 16 + cl;
#pragma unroll
        for (int ni = 0; ni < 4; ++ni) {
          const int sg = kt0 + ni * 16 + quad * 4;
#pragma unroll
          for (int r = 0; r < 4; ++r)
            if (sg + r > qg) sacc[mi][ni][r] = -1e30f;
        }
      }
    }
    float al[2];
#pragma unroll
    for (int mi = 0; mi < 2; ++mi) {
      float m0 = sacc[mi][0][0];
#pragma unroll
      for (int ni = 0; ni < 4; ++ni)
#pragma unroll
        for (int r = 0; r < 4; ++r) m0 = fmaxf(m0, sacc[mi][ni][r]);
      m0 = fmaxf(m0, __shfl_xor(m0, 16));
      m0 = fmaxf(m0, __shfl_xor(m0, 32));
      const float nm = fmaxf(m_[mi], m0);
      al[mi] = __builtin_amdgcn_exp2f(m_[mi] - nm);
      m_[mi] = nm;
      float ps = 0.f;
#pragma unroll
      for (int ni = 0; ni < 4; ++ni)
#pragma unroll
        for (int r = 0; r < 4; ++r) {
          const float p = __builtin_amdgcn_exp2f(sacc[mi][ni][r] - nm);
          sacc[mi][ni][r] = p;
          ps += p;
        }
      l_[mi] = l_[mi] * al[mi] + ps;
    }
#pragma unroll
    for (int mi = 0; mi < 2; ++mi)
#pragma unroll
      for (int ni = 0; ni < 4; ++ni) {
        f16x4 pk;
#pragma unroll
        for (int r = 0; r < 4; ++r) pk[r] = (f16)sacc[mi][ni][r];
        *reinterpret_cast<f16x4*>(&Ps[wv][mi * 16 + cl][ni * 16 + quad * 4]) = pk;
      }
#pragma unroll
    for (int mi = 0; mi < 2; ++mi)
#pragma unroll
      for (int dg = 0; dg < 8; ++dg) oacc[mi][dg] *= al[mi];
    asm volatile("s_waitcnt lgkmcnt(0)" ::: "memory");  // Ps is per-wave
    f16x8 bp[2][2];
#pragma unroll
    for (int mi = 0; mi < 2; ++mi)
#pragma unroll
      for (int kh = 0; kh < 2; ++kh)
        bp[mi][kh] =
            *reinterpret_cast<const f16x8*>(&Ps[wv][mi * 16 + cl][kh * 32 + quad * 8]);
#pragma unroll
    for (int kh = 0; kh < 2; ++kh)
#pragma unroll
      for (int dg = 0; dg < 8; ++dg) {
        const int gv = kh * 4 + quad;
        const int gvs = gv ^ (cl & 7);
        f16x8 av =
            *reinterpret_cast<const f16x8*>(Vs + (dg * 16 + cl) * 64 + gvs * 8);
#pragma unroll
        for (int mi = 0; mi < 2; ++mi)
          oacc[mi][dg] =
              __builtin_amdgcn_mfma_f32_16x16x32_f16(av, bp[mi][kh], oacc[mi][dg], 0, 0, 0);
      }
    __syncthreads();
  }
#pragma unroll
  for (int mi = 0; mi < 2; ++mi) {
    float l = l_[mi];
    l += __shfl_xor(l, 16);
    l += __shfl_xor(l, 32);
    const float inv = 1.0f / l;
    const size_t qg = qw0 + mi * 16 + cl;
#pragma unroll
    for (int dg = 0; dg < 8; ++dg) {
      f16x4 o;
#pragma unroll
      for (int r = 0; r < 4; ++r) o[r] = (f16)(oacc[mi][dg][r] * inv);
      *reinterpret_cast<f16x4*>(Ot + ((size_t)b * 2048 + qg) * 2048 + h * 128 +
                                dg * 16 + quad * 4) = o;
    }
  }
}

// ---------------------------------------------------------------------- launch
extern "C" void kernel_launch(void* const* d_in, const int* in_sizes, int n_in,
                              void* d_out, int out_size, void* d_ws, size_t ws_size,
                              hipStream_t stream) {
  (void)in_sizes; (void)n_in; (void)out_size; (void)ws_size;
  const float* hidden = (const float*)d_in[0];
  const float* cosT = (const float*)d_in[1];
  const float* sinT = (const float*)d_in[2];
  // d_in[3] = attention_mask: exactly causal triu * -1e9 -> computed analytically
  const float* Wq = (const float*)d_in[4];
  const float* Wk = (const float*)d_in[5];
  const float* Wv = (const float*)d_in[6];
  const float* Wo = (const float*)d_in[7];
  const float* qnw = (const float*)d_in[8];
  const float* knw = (const float*)d_in[9];
  float* out = (float*)d_out;

  char* ws = (char*)d_ws;
  size_t off = 0;
  auto alloc = [&](size_t bytes) {
    char* p = ws + off;
    off += (bytes + 255) & ~(size_t)255;
    return p;
  };
  f16* hb = (f16*)alloc(4096ull * 1024 * 2);
  f16* wqkv = (f16*)alloc(4096ull * 1024 * 2);   // [Wq;Wk;Wv] rows
  f16* wob = (f16*)alloc(1024ull * 2048 * 2);
  f16* qt = (f16*)alloc(32ull * 2048 * 128 * 2);
  f16* kt = (f16*)alloc(16ull * 2048 * 128 * 2);
  f16* vt = (f16*)alloc(16ull * 2048 * 128 * 2);
  f16* ot = (f16*)alloc(4096ull * 2048 * 2);

  cast_all<<<10240, 256, 0, stream>>>(hidden, Wq, Wk, Wv, Wo, hb, wqkv, wob);

  gemm_qkv<<<dim3(32, 32), 256, 0, stream>>>(hb, wqkv, qnw, knw, cosT, sinT,
                                             qt, kt, vt);

  attn<<<1024, 128, 0, stream>>>(qt, kt, vt, ot);

  gemm_bt64<<<dim3(8, 64), 256, 0, stream>>>(ot, wob, out, 4096, 1024, 2048);
}